// Round 2
// baseline (237.779 us; speedup 1.0000x reference)
//
#include <hip/hip_runtime.h>
#include <stdint.h>
#include <math.h>

// Problem constants (fixed by reference setup_inputs / reference()).
static constexpr int BB = 64;    // batch
static constexpr int TT = 4000;  // time
static constexpr int FF = 128;   // mel bins

// ---------------------------------------------------------------------------
// Threefry-2x32, 20 rounds — bit-exact replica of jax._src.prng.threefry2x32.
// ---------------------------------------------------------------------------
__host__ __device__ inline void tf2x32(uint32_t k0, uint32_t k1,
                                       uint32_t c0, uint32_t c1,
                                       uint32_t& o0, uint32_t& o1) {
  uint32_t ks2 = k0 ^ k1 ^ 0x1BD11BDAu;
  uint32_t x0 = c0 + k0;
  uint32_t x1 = c1 + k1;
#define TF_R(r) { x0 += x1; x1 = (x1 << (r)) | (x1 >> (32 - (r))); x1 ^= x0; }
  TF_R(13) TF_R(15) TF_R(26) TF_R(6)
  x0 += k1;  x1 += ks2 + 1u;
  TF_R(17) TF_R(29) TF_R(16) TF_R(24)
  x0 += ks2; x1 += k0 + 2u;
  TF_R(13) TF_R(15) TF_R(26) TF_R(6)
  x0 += k0;  x1 += k1 + 3u;
  TF_R(17) TF_R(29) TF_R(16) TF_R(24)
  x0 += k1;  x1 += ks2 + 4u;
  TF_R(13) TF_R(15) TF_R(26) TF_R(6)
  x0 += ks2; x1 += k0 + 5u;
#undef TF_R
  o0 = x0; o1 = x1;
}

// jax_threefry_partitionable=True (modern default) random_bits, 32-bit:
// element j uses counter pair (j>>32, j&0xffffffff) = (0, j) for j < 2^32,
// and the 32-bit output is the xor-fold o0 ^ o1 of the single block.
__host__ __device__ inline uint32_t rbits32_part(uint32_t k0, uint32_t k1, uint32_t j) {
  uint32_t o0, o1;
  tf2x32(k0, k1, 0u, j, o0, o1);
  return o0 ^ o1;
}

// jax.random.uniform f32: bitcast((bits >> 9) | 0x3F800000) - 1.0
__device__ inline float u01(uint32_t b) {
  return __uint_as_float((b >> 9) | 0x3F800000u) - 1.0f;
}

struct Keys {
  uint32_t k1f0, k1f1, k2f0, k2f1;  // randint(kf_w)'s internal split keys
  uint32_t kfs0, kfs1;              // kf_s (freq-start uniform)
  uint32_t ktw0, ktw1;              // kt_w (time-width uniform)
  uint32_t kts0, kts1;              // kt_s (time-start uniform)
};

__global__ __launch_bounds__(256)
void BatchSpecAugment_kernel(const float* __restrict__ mel,
                             const int* __restrict__ lengths,
                             float* __restrict__ out, Keys K) {
  __shared__ int s_valid;
  __shared__ int s_ts[2], s_te[2];
  __shared__ uint32_t s_fm[4];  // 128-bit freq mask

  const int b = blockIdx.y;

  if (threadIdx.x == 0) {
    const int vt = lengths[b];
    uint32_t fm0 = 0, fm1 = 0, fm2 = 0, fm3 = 0;
    for (int m = 0; m < 2; ++m) {
      const uint32_t j = (uint32_t)(2 * b + m);  // linear index into (64,2)
      // ---- frequency mask m: randint(kf_w, ..., 0, 31) semantics ----
      uint32_t hi = rbits32_part(K.k1f0, K.k1f1, j);
      uint32_t lo = rbits32_part(K.k2f0, K.k2f1, j);
      // span=31, multiplier=(2^16 % 31)^2 % 31 = 4
      int w = (int)(((hi % 31u) * 4u + (lo % 31u)) % 31u);
      float fu = u01(rbits32_part(K.kfs0, K.kfs1, j));
      int fs = (int)floorf(fu * (float)(FF - w + 1));
      if (w > 0) {  // fvalid: w>0 && w<F (w<=30 so second cond always true)
        for (int f = fs; f < fs + w; ++f) {
          if      (f < 32) fm0 |= 1u << f;
          else if (f < 64) fm1 |= 1u << (f - 32);
          else if (f < 96) fm2 |= 1u << (f - 64);
          else             fm3 |= 1u << (f - 96);
        }
      }
      // ---- time mask m ----
      int twmax = vt < 40 ? vt : 40;
      float tu = u01(rbits32_part(K.ktw0, K.ktw1, j));
      int tw = (int)floorf(tu * (float)(twmax + 1));
      if (tw > twmax) tw = twmax;
      float su = u01(rbits32_part(K.kts0, K.kts1, j));
      int sr = vt - tw + 1; if (sr < 1) sr = 1;
      int ts = (int)floorf(su * (float)sr);
      bool tv = (tw > 0) && (tw < vt) && (vt > 0);
      s_ts[m] = tv ? ts : 0x7FFFFFFF;       // sentinel: t >= INT_MAX never true
      s_te[m] = tv ? ts + tw : 0x7FFFFFFF;
    }
    s_valid = vt;
    s_fm[0] = fm0; s_fm[1] = fm1; s_fm[2] = fm2; s_fm[3] = fm3;
  }
  __syncthreads();

  const int lane = threadIdx.x & 31;   // 32 lanes x float4 = one 128-wide row
  const int r    = threadIdx.x >> 5;   // 8 rows per block-iteration
  const int c    = lane * 4;
  const uint32_t nibF = (s_fm[c >> 5] >> (c & 31)) & 0xFu;
  const int vt  = s_valid;
  const int ts0 = s_ts[0], te0 = s_te[0], ts1 = s_ts[1], te1 = s_te[1];

  const float4* __restrict__ mv = (const float4*)mel;
  float4* __restrict__       ov = (float4*)out;

  for (int g = blockIdx.x; g < TT / 8; g += gridDim.x) {
    const int t = g * 8 + r;
    const size_t idx = ((size_t)b * TT + t) * (FF / 4) + lane;
    float4 v = mv[idx];
    const bool tm = (t >= ts0 && t < te0) || (t >= ts1 && t < te1);
    const uint32_t nib = tm ? 0xFu : (t < vt ? nibF : 0u);
    float4 o;
    o.x = (nib & 1u) ? 0.0f : v.x;
    o.y = (nib & 2u) ? 0.0f : v.y;
    o.z = (nib & 4u) ? 0.0f : v.z;
    o.w = (nib & 8u) ? 0.0f : v.w;
    ov[idx] = o;
  }
}

extern "C" void kernel_launch(void* const* d_in, const int* in_sizes, int n_in,
                              void* d_out, int out_size, void* d_ws, size_t ws_size,
                              hipStream_t stream) {
  (void)in_sizes; (void)n_in; (void)out_size; (void)d_ws; (void)ws_size;

  // --- host-side key derivation (pure uint32 math; graph-capture safe) ---
  // jax_threefry_partitionable=True fold-like split:
  //   split(key, n)[i] = threefry(key, counter=(0, i)) -> (o0, o1)
  // key = jax.random.key(42) -> (0, 42)
  uint32_t kfw0, kfw1, kfs0, kfs1, ktw0, ktw1, kts0, kts1;
  tf2x32(0u, 42u, 0u, 0u, kfw0, kfw1);  // kf_w
  tf2x32(0u, 42u, 0u, 1u, kfs0, kfs1);  // kf_s
  tf2x32(0u, 42u, 0u, 2u, ktw0, ktw1);  // kt_w
  tf2x32(0u, 42u, 0u, 3u, kts0, kts1);  // kt_s

  // randint(kf_w, ...) internally does k1, k2 = split(kf_w) (fold-like):
  uint32_t k1f0, k1f1, k2f0, k2f1;
  tf2x32(kfw0, kfw1, 0u, 0u, k1f0, k1f1);  // higher_bits key
  tf2x32(kfw0, kfw1, 0u, 1u, k2f0, k2f1);  // lower_bits key

  Keys K;
  K.k1f0 = k1f0; K.k1f1 = k1f1;
  K.k2f0 = k2f0; K.k2f1 = k2f1;
  K.kfs0 = kfs0; K.kfs1 = kfs1;
  K.ktw0 = ktw0; K.ktw1 = ktw1;
  K.kts0 = kts0; K.kts1 = kts1;

  const float* mel     = (const float*)d_in[0];
  const int*   lengths = (const int*)d_in[1];
  float*       outp    = (float*)d_out;

  dim3 grid(32, BB), block(256);
  BatchSpecAugment_kernel<<<grid, block, 0, stream>>>(mel, lengths, outp, K);
}

// Round 4
// 231.740 us; speedup vs baseline: 1.0261x; 1.0261x over previous
//
#include <hip/hip_runtime.h>
#include <stdint.h>
#include <math.h>

// Problem constants (fixed by reference setup_inputs / reference()).
static constexpr int BB = 64;    // batch
static constexpr int TT = 4000;  // time
static constexpr int FF = 128;   // mel bins

// Native clang vector type — required by __builtin_nontemporal_store
// (HIP_vector_type float4 is a struct and is rejected).
typedef float floatx4 __attribute__((ext_vector_type(4)));

// ---------------------------------------------------------------------------
// Threefry-2x32, 20 rounds — bit-exact replica of jax._src.prng.threefry2x32.
// ---------------------------------------------------------------------------
__host__ __device__ inline void tf2x32(uint32_t k0, uint32_t k1,
                                       uint32_t c0, uint32_t c1,
                                       uint32_t& o0, uint32_t& o1) {
  uint32_t ks2 = k0 ^ k1 ^ 0x1BD11BDAu;
  uint32_t x0 = c0 + k0;
  uint32_t x1 = c1 + k1;
#define TF_R(r) { x0 += x1; x1 = (x1 << (r)) | (x1 >> (32 - (r))); x1 ^= x0; }
  TF_R(13) TF_R(15) TF_R(26) TF_R(6)
  x0 += k1;  x1 += ks2 + 1u;
  TF_R(17) TF_R(29) TF_R(16) TF_R(24)
  x0 += ks2; x1 += k0 + 2u;
  TF_R(13) TF_R(15) TF_R(26) TF_R(6)
  x0 += k0;  x1 += k1 + 3u;
  TF_R(17) TF_R(29) TF_R(16) TF_R(24)
  x0 += k1;  x1 += ks2 + 4u;
  TF_R(13) TF_R(15) TF_R(26) TF_R(6)
  x0 += ks2; x1 += k0 + 5u;
#undef TF_R
  o0 = x0; o1 = x1;
}

// jax_threefry_partitionable=True random_bits, 32-bit: element j uses counter
// (0, j); output is the xor-fold o0 ^ o1.  [verified bit-exact in R2]
__host__ __device__ inline uint32_t rbits32_part(uint32_t k0, uint32_t k1, uint32_t j) {
  uint32_t o0, o1;
  tf2x32(k0, k1, 0u, j, o0, o1);
  return o0 ^ o1;
}

// jax.random.uniform f32: bitcast((bits >> 9) | 0x3F800000) - 1.0
__device__ inline float u01(uint32_t b) {
  return __uint_as_float((b >> 9) | 0x3F800000u) - 1.0f;
}

struct Keys {
  uint32_t k1f0, k1f1, k2f0, k2f1;  // randint(kf_w)'s internal split keys
  uint32_t kfs0, kfs1;              // kf_s (freq-start uniform)
  uint32_t ktw0, ktw1;              // kt_w (time-width uniform)
  uint32_t kts0, kts1;              // kt_s (time-start uniform)
};

// Block = 256 threads covers 32 t-rows x 128 f (16 KB).  Each thread: 4
// independent 16B loads issued up-front (64 B in flight), then 4 masked
// non-temporal stores.  grid = (125, 64) = 8000 blocks ~= 31/CU.
__global__ __launch_bounds__(256)
void BatchSpecAugment_kernel(const floatx4* __restrict__ mv,
                             const int* __restrict__ lengths,
                             floatx4* __restrict__ ov, Keys K) {
  __shared__ int s_valid;
  __shared__ int s_ts[2], s_te[2];
  __shared__ uint32_t s_fm[4];  // 128-bit freq mask

  const int b = blockIdx.y;

  if (threadIdx.x == 0) {
    const int vt = lengths[b];
    uint32_t fm0 = 0, fm1 = 0, fm2 = 0, fm3 = 0;
    for (int m = 0; m < 2; ++m) {
      const uint32_t j = (uint32_t)(2 * b + m);  // linear index into (64,2)
      // ---- frequency mask m: randint span=31, multiplier=4 ----
      uint32_t hi = rbits32_part(K.k1f0, K.k1f1, j);
      uint32_t lo = rbits32_part(K.k2f0, K.k2f1, j);
      int w = (int)(((hi % 31u) * 4u + (lo % 31u)) % 31u);
      float fu = u01(rbits32_part(K.kfs0, K.kfs1, j));
      int fs = (int)floorf(fu * (float)(FF - w + 1));
      if (w > 0) {
        for (int f = fs; f < fs + w; ++f) {
          if      (f < 32) fm0 |= 1u << f;
          else if (f < 64) fm1 |= 1u << (f - 32);
          else if (f < 96) fm2 |= 1u << (f - 64);
          else             fm3 |= 1u << (f - 96);
        }
      }
      // ---- time mask m ----
      int twmax = vt < 40 ? vt : 40;
      float tu = u01(rbits32_part(K.ktw0, K.ktw1, j));
      int tw = (int)floorf(tu * (float)(twmax + 1));
      if (tw > twmax) tw = twmax;
      float su = u01(rbits32_part(K.kts0, K.kts1, j));
      int sr = vt - tw + 1; if (sr < 1) sr = 1;
      int ts = (int)floorf(su * (float)sr);
      bool tv = (tw > 0) && (tw < vt) && (vt > 0);
      s_ts[m] = tv ? ts : 0x7FFFFFFF;
      s_te[m] = tv ? ts + tw : 0x7FFFFFFF;
    }
    s_valid = vt;
    s_fm[0] = fm0; s_fm[1] = fm1; s_fm[2] = fm2; s_fm[3] = fm3;
  }
  __syncthreads();

  const int lane = threadIdx.x & 31;   // f position (16B granules)
  const int r    = threadIdx.x >> 5;   // row 0..7 within 8-row group
  const int c    = lane * 4;
  const uint32_t nibF = (s_fm[c >> 5] >> (c & 31)) & 0xFu;
  const int vt  = s_valid;
  const int ts0 = s_ts[0], te0 = s_te[0], ts1 = s_ts[1], te1 = s_te[1];

  const int t0 = blockIdx.x * 32 + r;            // rows t0 + 8k, k = 0..3
  const size_t base = ((size_t)b * TT + t0) * (FF / 4) + lane;

  floatx4 v[4];
#pragma unroll
  for (int k = 0; k < 4; ++k) v[k] = mv[base + (size_t)k * 8 * (FF / 4)];

#pragma unroll
  for (int k = 0; k < 4; ++k) {
    const int t = t0 + 8 * k;
    const bool tm = (t >= ts0 && t < te0) || (t >= ts1 && t < te1);
    const uint32_t nib = tm ? 0xFu : (t < vt ? nibF : 0u);
    floatx4 o;
    o.x = (nib & 1u) ? 0.0f : v[k].x;
    o.y = (nib & 2u) ? 0.0f : v[k].y;
    o.z = (nib & 4u) ? 0.0f : v[k].z;
    o.w = (nib & 8u) ? 0.0f : v[k].w;
    __builtin_nontemporal_store(o, &ov[base + (size_t)k * 8 * (FF / 4)]);
  }
}

extern "C" void kernel_launch(void* const* d_in, const int* in_sizes, int n_in,
                              void* d_out, int out_size, void* d_ws, size_t ws_size,
                              hipStream_t stream) {
  (void)in_sizes; (void)n_in; (void)out_size; (void)d_ws; (void)ws_size;

  // Host-side key derivation (partitionable threefry; verified R2).
  uint32_t kfw0, kfw1, kfs0, kfs1, ktw0, ktw1, kts0, kts1;
  tf2x32(0u, 42u, 0u, 0u, kfw0, kfw1);  // kf_w
  tf2x32(0u, 42u, 0u, 1u, kfs0, kfs1);  // kf_s
  tf2x32(0u, 42u, 0u, 2u, ktw0, ktw1);  // kt_w
  tf2x32(0u, 42u, 0u, 3u, kts0, kts1);  // kt_s

  uint32_t k1f0, k1f1, k2f0, k2f1;
  tf2x32(kfw0, kfw1, 0u, 0u, k1f0, k1f1);  // randint higher_bits key
  tf2x32(kfw0, kfw1, 0u, 1u, k2f0, k2f1);  // randint lower_bits key

  Keys K;
  K.k1f0 = k1f0; K.k1f1 = k1f1;
  K.k2f0 = k2f0; K.k2f1 = k2f1;
  K.kfs0 = kfs0; K.kfs1 = kfs1;
  K.ktw0 = ktw0; K.ktw1 = ktw1;
  K.kts0 = kts0; K.kts1 = kts1;

  const floatx4* mel     = (const floatx4*)d_in[0];
  const int*     lengths = (const int*)d_in[1];
  floatx4*       outp    = (floatx4*)d_out;

  dim3 grid(TT / 32, BB), block(256);
  BatchSpecAugment_kernel<<<grid, block, 0, stream>>>(mel, lengths, outp, K);
}